// Round 3
// baseline (648.651 us; speedup 1.0000x reference)
//
#include <hip/hip_runtime.h>

// Problem constants
#define TT 16
#define NN 50000
#define FF 64
#define EE 131072
#define NR (TT*NN)            // 800000 (j,row) pairs
#define NEDGE (TT*EE)         // 2097152 edges total
#define SCAN_NBLK ((NR + 1023) / 1024)   // 782

typedef __attribute__((ext_vector_type(8))) short bf16x8;
typedef __attribute__((ext_vector_type(4))) short bf16x4;
typedef __attribute__((ext_vector_type(4))) float f32x4;

__device__ __forceinline__ unsigned short f2bf(float f) {
    union { float f; unsigned u; } v; v.f = f;
    return (unsigned short)((v.u + 0x7FFFu + ((v.u >> 16) & 1u)) >> 16);  // RNE
}

// K=16 bf16 MFMA. A: lane holds A[m=lane&15][k=(lane>>4)*4+j];
// B: B[k=(lane>>4)*4+j][n=lane&15]; C/D: row=(lane>>4)*4+reg, col=lane&15.
// (Both operand mappings HW-validated by round-2 pass.)
__device__ __forceinline__ f32x4 mfma16x16x16bf16(bf16x4 a, bf16x4 b, f32x4 c) {
#if __has_builtin(__builtin_amdgcn_mfma_f32_16x16x16bf16_1k)
    return __builtin_amdgcn_mfma_f32_16x16x16bf16_1k(a, b, c, 0, 0, 0);
#elif __has_builtin(__builtin_amdgcn_mfma_f32_16x16x16_bf16)
    return __builtin_amdgcn_mfma_f32_16x16x16_bf16(a, b, c, 0, 0, 0);
#else
    f32x4 d;
    asm volatile("v_mfma_f32_16x16x16_bf16 %0, %1, %2, %3\n\ts_nop 7\n\ts_nop 7"
                 : "=&v"(d) : "v"(a), "v"(b), "v"(c));
    return d;
#endif
}

// ---------------------------------------------------------------------------
// K1: Yt[k][node][fo] = sum_s M[k,s] * sum_fi x[s][node][fi] * W[fi][fo]
// One wave per node, fully in-register. Mix MFMA computes (M@P)^T so each
// lane holds 4 contiguous fo of one k-slice -> packed 8B stores.
// ---------------------------------------------------------------------------
__global__ __launch_bounds__(256) void k1_proj_mix(
    const float* __restrict__ x, const float* __restrict__ M,
    const float* __restrict__ W, unsigned short* __restrict__ Yt)
{
    const int tid  = threadIdx.x;
    const int wid  = tid >> 6;
    const int lane = tid & 63;
    const int col  = lane & 15;   // MFMA m/n index
    const int grp  = lane >> 4;   // MFMA k-group

    // W as B-frags for 16x16x32: lane holds B[k=q*32+grp*8+j][n=t*16+col]
    bf16x8 bw[2][4];
#pragma unroll
    for (int q = 0; q < 2; ++q)
#pragma unroll
        for (int t = 0; t < 4; ++t)
#pragma unroll
            for (int j = 0; j < 8; ++j)
                bw[q][t][j] = (short)f2bf(W[(q*32 + grp*8 + j)*FF + t*16 + col]);

    // M fragment: element j = M[col][grp*4+j].
    // As B-frag of the mix MFMA: B[k=grp*4+j][n=col] = M^T[k][n].
    bf16x4 mf;
#pragma unroll
    for (int j = 0; j < 4; ++j) mf[j] = (short)f2bf(M[col*16 + grp*4 + j]);

    const f32x4 zero = {0.f, 0.f, 0.f, 0.f};
    const int nwaves = gridDim.x * 4;

    for (int node = blockIdx.x*4 + wid; node < NN; node += nwaves) {
        // ---- load x rows direct to A-frags: lane reads row s=col, fi = q*32+grp*8+(0..7) ----
        const float* xb = x + (size_t)col*NN*FF + (size_t)node*FF + grp*8;
        float4 v0 = *reinterpret_cast<const float4*>(xb);
        float4 v1 = *reinterpret_cast<const float4*>(xb + 4);
        float4 v2 = *reinterpret_cast<const float4*>(xb + 32);
        float4 v3 = *reinterpret_cast<const float4*>(xb + 36);
        bf16x8 a0, a1;
        a0[0] = (short)f2bf(v0.x); a0[1] = (short)f2bf(v0.y);
        a0[2] = (short)f2bf(v0.z); a0[3] = (short)f2bf(v0.w);
        a0[4] = (short)f2bf(v1.x); a0[5] = (short)f2bf(v1.y);
        a0[6] = (short)f2bf(v1.z); a0[7] = (short)f2bf(v1.w);
        a1[0] = (short)f2bf(v2.x); a1[1] = (short)f2bf(v2.y);
        a1[2] = (short)f2bf(v2.z); a1[3] = (short)f2bf(v2.w);
        a1[4] = (short)f2bf(v3.x); a1[5] = (short)f2bf(v3.y);
        a1[6] = (short)f2bf(v3.z); a1[7] = (short)f2bf(v3.w);

        // ---- P[s][fo] = X @ W via 16x16x32 MFMA (K=64 in 2 steps, 4 fo-tiles) ----
        f32x4 acc[4];
#pragma unroll
        for (int t = 0; t < 4; ++t) acc[t] = zero;
#pragma unroll
        for (int t = 0; t < 4; ++t)
            acc[t] = __builtin_amdgcn_mfma_f32_16x16x32_bf16(a0, bw[0][t], acc[t], 0, 0, 0);
#pragma unroll
        for (int t = 0; t < 4; ++t)
            acc[t] = __builtin_amdgcn_mfma_f32_16x16x32_bf16(a1, bw[1][t], acc[t], 0, 0, 0);

        // ---- Y^T = P_t^T @ M^T via 16x16x16 MFMA (P C-layout IS the A-frag layout).
        //      Lane holds Y[k=col][fo = t*16 + grp*4 + rr], rr=0..3 -> packed 8B store.
#pragma unroll
        for (int t = 0; t < 4; ++t) {
            bf16x4 pb;
#pragma unroll
            for (int rr = 0; rr < 4; ++rr) pb[rr] = (short)f2bf(acc[t][rr]);
            f32x4 y = mfma16x16x16bf16(pb, mf, zero);
            unsigned lo = (unsigned)f2bf(y[0]) | ((unsigned)f2bf(y[1]) << 16);
            unsigned hi = (unsigned)f2bf(y[2]) | ((unsigned)f2bf(y[3]) << 16);
            uint2 st; st.x = lo; st.y = hi;
            *reinterpret_cast<uint2*>(Yt + (size_t)col*NN*FF + (size_t)node*FF + t*16 + grp*4) = st;
        }
    }
}

// ---------------------------------------------------------------------------
// CSR build: count -> scan (3 phase) -> fill
// ---------------------------------------------------------------------------
__global__ __launch_bounds__(256) void count_kernel(const int* __restrict__ rows,
                                                    int* __restrict__ cnt)
{
    int i = blockIdx.x*256 + threadIdx.x;
    const int stride = gridDim.x*256;
    for (; i < NEDGE; i += stride) {
        const int j = i >> 17;            // EE = 2^17
        atomicAdd(&cnt[j*NN + rows[i]], 1);
    }
}

__global__ __launch_bounds__(256) void scan1(const int* __restrict__ cnt, int* __restrict__ part)
{
    __shared__ int sd[256];
    const int t = threadIdx.x;
    const int base = blockIdx.x*1024 + t*4;
    int s = 0;
    if (base + 3 < NR) {
        int4 v = *reinterpret_cast<const int4*>(cnt + base);
        s = v.x + v.y + v.z + v.w;
    } else if (base < NR) {
        for (int u = 0; u < 4; ++u) if (base + u < NR) s += cnt[base + u];
    }
    sd[t] = s; __syncthreads();
#pragma unroll
    for (int o = 128; o > 0; o >>= 1) {
        if (t < o) sd[t] += sd[t + o];
        __syncthreads();
    }
    if (t == 0) part[blockIdx.x] = sd[0];
}

__global__ __launch_bounds__(1024) void scan2(int* __restrict__ part)
{
    __shared__ int sd[1024];
    const int t = threadIdx.x;
    sd[t] = (t < SCAN_NBLK) ? part[t] : 0;
    __syncthreads();
#pragma unroll
    for (int o = 1; o < 1024; o <<= 1) {
        int v = (t >= o) ? sd[t - o] : 0;
        __syncthreads();
        sd[t] += v;
        __syncthreads();
    }
    part[t] = (t == 0) ? 0 : sd[t - 1];   // exclusive block prefix
}

__global__ __launch_bounds__(256) void scan3(const int* __restrict__ cnt, const int* __restrict__ part,
                                             int* __restrict__ offs, int* __restrict__ cur)
{
    __shared__ int sd[256];
    const int t = threadIdx.x;
    const int base = blockIdx.x*1024 + t*4;
    int v0 = 0, v1 = 0, v2 = 0, v3 = 0;
    if (base + 3 < NR) {
        int4 v = *reinterpret_cast<const int4*>(cnt + base);
        v0 = v.x; v1 = v.y; v2 = v.z; v3 = v.w;
    } else if (base < NR) {
        v0 = cnt[base];
        if (base + 1 < NR) v1 = cnt[base + 1];
        if (base + 2 < NR) v2 = cnt[base + 2];
    }
    sd[t] = v0 + v1 + v2 + v3;
    __syncthreads();
#pragma unroll
    for (int o = 1; o < 256; o <<= 1) {
        int vv = (t >= o) ? sd[t - o] : 0;
        __syncthreads();
        sd[t] += vv;
        __syncthreads();
    }
    const int excl = (t == 0) ? 0 : sd[t - 1];
    const int off = part[blockIdx.x] + excl;
    const int o0 = off, o1 = off + v0, o2 = off + v0 + v1, o3 = off + v0 + v1 + v2;
    if (base + 3 < NR) {
        int4 ov; ov.x = o0; ov.y = o1; ov.z = o2; ov.w = o3;
        *reinterpret_cast<int4*>(offs + base) = ov;
        *reinterpret_cast<int4*>(cur + base) = ov;
    } else if (base < NR) {
        offs[base] = o0; cur[base] = o0;
        if (base + 1 < NR) { offs[base+1] = o1; cur[base+1] = o1; }
        if (base + 2 < NR) { offs[base+2] = o2; cur[base+2] = o2; }
    }
}

__global__ __launch_bounds__(256) void fill_kernel(const int* __restrict__ rows,
                                                   const int* __restrict__ cols,
                                                   const float* __restrict__ vals,
                                                   int* __restrict__ cur,
                                                   int2* __restrict__ csr)
{
    int i = blockIdx.x*256 + threadIdx.x;
    const int stride = gridDim.x*256;
    for (; i < NEDGE; i += stride) {
        const int j = i >> 17;
        const int pos = atomicAdd(&cur[j*NN + rows[i]], 1);
        int2 ent; ent.x = cols[i]; ent.y = __float_as_int(vals[i]);
        csr[pos] = ent;
    }
}

// ---------------------------------------------------------------------------
// K2: out[k][r][:] = sum_{d=0..2, j=k-d>=0} M[k,j] * sum_{e in CSR_j(r)} v_e * Yt[k][c_e][:]
// One wave per (k,row): 64 lanes = 4 edge-slots x 16 feature-lanes.
// The 3 band segments are walked as one concatenated list, 4 edges/iter,
// then a 2-step shfl_xor reduction across edge-slots. Pure gather, no atomics.
// ---------------------------------------------------------------------------
__global__ __launch_bounds__(256) void k2_spmm(
    const unsigned short* __restrict__ Yt, const float* __restrict__ M,
    const int* __restrict__ offs, const int* __restrict__ cnt,
    const int2* __restrict__ csr, float* __restrict__ out)
{
    const int wid  = threadIdx.x >> 6;
    const int lane = threadIdx.x & 63;
    const int esub = lane >> 4;   // edge slot 0..3
    const int fq   = lane & 15;   // feature quad: f = fq*4 .. fq*4+3
    const int k = blockIdx.y;
    const int r = __builtin_amdgcn_readfirstlane(blockIdx.x*4 + wid);  // wave-uniform row
    const unsigned short* __restrict__ Yb = Yt + (size_t)k*NN*FF;

    int n0, n1, n2, b0, b1, b2; float w0, w1, w2;
    {
        b0 = offs[k*NN + r];        n0 = cnt[k*NN + r];        w0 = M[k*16 + k];
        const bool ok1 = (k >= 1);
        const int j1 = ok1 ? k - 1 : 0;
        b1 = offs[j1*NN + r];       n1 = ok1 ? cnt[j1*NN + r] : 0;  w1 = ok1 ? M[k*16 + j1] : 0.f;
        const bool ok2 = (k >= 2);
        const int j2 = ok2 ? k - 2 : 0;
        b2 = offs[j2*NN + r];       n2 = ok2 ? cnt[j2*NN + r] : 0;  w2 = ok2 ? M[k*16 + j2] : 0.f;
    }
    const int c01  = n0 + n1;
    const int ntot = c01 + n2;

    float a0 = 0.f, a1 = 0.f, a2 = 0.f, a3 = 0.f;
    for (int p0 = 0; p0 < ntot; p0 += 4) {
        const int p = p0 + esub;
        const bool act = (p < ntot);
        const int pc = act ? p : (ntot - 1);
        int base; float wd;
        if (pc < n0)       { base = b0 + pc;        wd = w0; }
        else if (pc < c01) { base = b1 + pc - n0;   wd = w1; }
        else               { base = b2 + pc - c01;  wd = w2; }
        const int2 ent = csr[base];
        const float wv = act ? wd * __int_as_float(ent.y) : 0.f;
        const uint2 uv = *reinterpret_cast<const uint2*>(Yb + (size_t)ent.x*FF + fq*4);
        a0 = fmaf(wv, __uint_as_float(uv.x << 16), a0);
        a1 = fmaf(wv, __uint_as_float(uv.x & 0xFFFF0000u), a1);
        a2 = fmaf(wv, __uint_as_float(uv.y << 16), a2);
        a3 = fmaf(wv, __uint_as_float(uv.y & 0xFFFF0000u), a3);
    }
    a0 += __shfl_xor(a0, 16); a0 += __shfl_xor(a0, 32);
    a1 += __shfl_xor(a1, 16); a1 += __shfl_xor(a1, 32);
    a2 += __shfl_xor(a2, 16); a2 += __shfl_xor(a2, 32);
    a3 += __shfl_xor(a3, 16); a3 += __shfl_xor(a3, 32);
    if (esub == 0) {
        float4 res; res.x = a0; res.y = a1; res.z = a2; res.w = a3;
        *reinterpret_cast<float4*>(out + ((size_t)k*NN + r)*FF + fq*4) = res;
    }
}

// ---------------------------------------------------------------------------
extern "C" void kernel_launch(void* const* d_in, const int* in_sizes, int n_in,
                              void* d_out, int out_size, void* d_ws, size_t ws_size,
                              hipStream_t stream) {
    (void)in_sizes; (void)n_in; (void)out_size; (void)ws_size;
    const float* x     = (const float*)d_in[0];
    const float* M     = (const float*)d_in[1];
    const float* avals = (const float*)d_in[2];
    const float* W     = (const float*)d_in[3];
    const int*   arows = (const int*)d_in[4];
    const int*   acols = (const int*)d_in[5];
    float* out = (float*)d_out;

    // workspace carve (total ~128.8 MB)
    char* ws = (char*)d_ws;
    size_t o = 0;
    unsigned short* Yt = (unsigned short*)(ws + o); o += (size_t)TT*NN*FF*2;  // 102.4 MB
    o = (o + 255) & ~(size_t)255;
    int* cnt  = (int*)(ws + o); o += (size_t)NR*4; o = (o + 255) & ~(size_t)255;
    int* offs = (int*)(ws + o); o += (size_t)NR*4; o = (o + 255) & ~(size_t)255;
    int* cur  = (int*)(ws + o); o += (size_t)NR*4; o = (o + 255) & ~(size_t)255;
    int* part = (int*)(ws + o); o += 4096;          o = (o + 255) & ~(size_t)255;
    int2* csr = (int2*)(ws + o);                    // 16.8 MB

    hipMemsetAsync(cnt, 0, (size_t)NR*4, stream);
    hipLaunchKernelGGL(k1_proj_mix, dim3(2048), dim3(256), 0, stream, x, M, W, Yt);
    hipLaunchKernelGGL(count_kernel, dim3(2048), dim3(256), 0, stream, arows, cnt);
    hipLaunchKernelGGL(scan1, dim3(SCAN_NBLK), dim3(256), 0, stream, cnt, part);
    hipLaunchKernelGGL(scan2, dim3(1), dim3(1024), 0, stream, part);
    hipLaunchKernelGGL(scan3, dim3(SCAN_NBLK), dim3(256), 0, stream, cnt, part, offs, cur);
    hipLaunchKernelGGL(fill_kernel, dim3(2048), dim3(256), 0, stream, arows, acols, avals, cur, csr);
    hipLaunchKernelGGL(k2_spmm, dim3(12500, 16), dim3(256), 0, stream, Yt, M, offs, cnt, csr, out);
}

// Round 4
// 617.573 us; speedup vs baseline: 1.0503x; 1.0503x over previous
//
#include <hip/hip_runtime.h>

// Problem constants
#define TT 16
#define NN 50000
#define FF 64
#define EE 131072
#define NR (TT*NN)            // 800000 (r,j) pairs
#define NEDGE (TT*EE)         // 2097152 edges total
#define SCAN_NBLK ((NR + 1023) / 1024)   // 782

typedef __attribute__((ext_vector_type(8))) short bf16x8;
typedef __attribute__((ext_vector_type(4))) short bf16x4;
typedef __attribute__((ext_vector_type(4))) float f32x4;

__device__ __forceinline__ unsigned short f2bf(float f) {
    union { float f; unsigned u; } v; v.f = f;
    return (unsigned short)((v.u + 0x7FFFu + ((v.u >> 16) & 1u)) >> 16);  // RNE
}
__device__ __forceinline__ float lo16f(unsigned u) { return __uint_as_float(u << 16); }
__device__ __forceinline__ float hi16f(unsigned u) { return __uint_as_float(u & 0xFFFF0000u); }

// K=16 bf16 MFMA. A: lane holds A[m=lane&15][k=(lane>>4)*4+j];
// B: B[k=(lane>>4)*4+j][n=lane&15]; C/D: row=(lane>>4)*4+reg, col=lane&15.
__device__ __forceinline__ f32x4 mfma16x16x16bf16(bf16x4 a, bf16x4 b, f32x4 c) {
#if __has_builtin(__builtin_amdgcn_mfma_f32_16x16x16bf16_1k)
    return __builtin_amdgcn_mfma_f32_16x16x16bf16_1k(a, b, c, 0, 0, 0);
#elif __has_builtin(__builtin_amdgcn_mfma_f32_16x16x16_bf16)
    return __builtin_amdgcn_mfma_f32_16x16x16_bf16(a, b, c, 0, 0, 0);
#else
    f32x4 d;
    asm volatile("v_mfma_f32_16x16x16_bf16 %0, %1, %2, %3\n\ts_nop 7\n\ts_nop 7"
                 : "=&v"(d) : "v"(a), "v"(b), "v"(c));
    return d;
#endif
}

// ---------------------------------------------------------------------------
// K1: Yt[node][k][fo] (node-major!) = sum_s M[k,s] * sum_fi x[s][node][fi]*W[fi][fo]
// One wave per node, fully in-register; mix MFMA computes (M@P)^T -> packed 8B stores.
// ---------------------------------------------------------------------------
__global__ __launch_bounds__(256) void k1_proj_mix(
    const float* __restrict__ x, const float* __restrict__ M,
    const float* __restrict__ W, unsigned short* __restrict__ Yt)
{
    const int tid  = threadIdx.x;
    const int wid  = tid >> 6;
    const int lane = tid & 63;
    const int col  = lane & 15;   // MFMA m/n index
    const int grp  = lane >> 4;   // MFMA k-group

    // W as B-frags for 16x16x32: lane holds B[k=q*32+grp*8+j][n=t*16+col]
    bf16x8 bw[2][4];
#pragma unroll
    for (int q = 0; q < 2; ++q)
#pragma unroll
        for (int t = 0; t < 4; ++t)
#pragma unroll
            for (int j = 0; j < 8; ++j)
                bw[q][t][j] = (short)f2bf(W[(q*32 + grp*8 + j)*FF + t*16 + col]);

    // M fragment: element j = M[col][grp*4+j] (B-frag of mix MFMA = M^T)
    bf16x4 mf;
#pragma unroll
    for (int j = 0; j < 4; ++j) mf[j] = (short)f2bf(M[col*16 + grp*4 + j]);

    const f32x4 zero = {0.f, 0.f, 0.f, 0.f};
    const int nwaves = gridDim.x * 4;

    for (int node = blockIdx.x*4 + wid; node < NN; node += nwaves) {
        // ---- load x rows direct to A-frags: lane reads row s=col, fi = q*32+grp*8+(0..7) ----
        const float* xb = x + (size_t)col*NN*FF + (size_t)node*FF + grp*8;
        float4 v0 = *reinterpret_cast<const float4*>(xb);
        float4 v1 = *reinterpret_cast<const float4*>(xb + 4);
        float4 v2 = *reinterpret_cast<const float4*>(xb + 32);
        float4 v3 = *reinterpret_cast<const float4*>(xb + 36);
        bf16x8 a0, a1;
        a0[0] = (short)f2bf(v0.x); a0[1] = (short)f2bf(v0.y);
        a0[2] = (short)f2bf(v0.z); a0[3] = (short)f2bf(v0.w);
        a0[4] = (short)f2bf(v1.x); a0[5] = (short)f2bf(v1.y);
        a0[6] = (short)f2bf(v1.z); a0[7] = (short)f2bf(v1.w);
        a1[0] = (short)f2bf(v2.x); a1[1] = (short)f2bf(v2.y);
        a1[2] = (short)f2bf(v2.z); a1[3] = (short)f2bf(v2.w);
        a1[4] = (short)f2bf(v3.x); a1[5] = (short)f2bf(v3.y);
        a1[6] = (short)f2bf(v3.z); a1[7] = (short)f2bf(v3.w);

        // ---- P[s][fo] = X @ W via 16x16x32 MFMA (K=64 in 2 steps, 4 fo-tiles) ----
        f32x4 acc[4];
#pragma unroll
        for (int t = 0; t < 4; ++t) acc[t] = zero;
#pragma unroll
        for (int t = 0; t < 4; ++t)
            acc[t] = __builtin_amdgcn_mfma_f32_16x16x32_bf16(a0, bw[0][t], acc[t], 0, 0, 0);
#pragma unroll
        for (int t = 0; t < 4; ++t)
            acc[t] = __builtin_amdgcn_mfma_f32_16x16x32_bf16(a1, bw[1][t], acc[t], 0, 0, 0);

        // ---- Y^T = P^T @ M^T: lane holds Y[k=col][fo=t*16+grp*4+rr] -> packed 8B store,
        //      node-major layout: Yt[node*1024 + k*64 + fo]
#pragma unroll
        for (int t = 0; t < 4; ++t) {
            bf16x4 pb;
#pragma unroll
            for (int rr = 0; rr < 4; ++rr) pb[rr] = (short)f2bf(acc[t][rr]);
            f32x4 y = mfma16x16x16bf16(pb, mf, zero);
            unsigned lo = (unsigned)f2bf(y[0]) | ((unsigned)f2bf(y[1]) << 16);
            unsigned hi = (unsigned)f2bf(y[2]) | ((unsigned)f2bf(y[3]) << 16);
            uint2 st; st.x = lo; st.y = hi;
            *reinterpret_cast<uint2*>(Yt + (size_t)node*1024 + col*64 + t*16 + grp*4) = st;
        }
    }
}

// ---------------------------------------------------------------------------
// CSR build with row-major (r,j) indexing: cnt/offs/cur at [r*16 + j].
// csr entries of one row r (all 16 j lists) end up contiguous.
// ---------------------------------------------------------------------------
__global__ __launch_bounds__(256) void count_kernel(const int* __restrict__ rows,
                                                    int* __restrict__ cnt)
{
    int i = blockIdx.x*256 + threadIdx.x;
    const int stride = gridDim.x*256;
    for (; i < NEDGE; i += stride) {
        const int j = i >> 17;            // EE = 2^17
        atomicAdd(&cnt[rows[i]*16 + j], 1);
    }
}

__global__ __launch_bounds__(256) void scan1(const int* __restrict__ cnt, int* __restrict__ part)
{
    __shared__ int sd[256];
    const int t = threadIdx.x;
    const int base = blockIdx.x*1024 + t*4;
    int s = 0;
    if (base + 3 < NR) {
        int4 v = *reinterpret_cast<const int4*>(cnt + base);
        s = v.x + v.y + v.z + v.w;
    } else if (base < NR) {
        for (int u = 0; u < 4; ++u) if (base + u < NR) s += cnt[base + u];
    }
    sd[t] = s; __syncthreads();
#pragma unroll
    for (int o = 128; o > 0; o >>= 1) {
        if (t < o) sd[t] += sd[t + o];
        __syncthreads();
    }
    if (t == 0) part[blockIdx.x] = sd[0];
}

__global__ __launch_bounds__(1024) void scan2(int* __restrict__ part)
{
    __shared__ int sd[1024];
    const int t = threadIdx.x;
    sd[t] = (t < SCAN_NBLK) ? part[t] : 0;
    __syncthreads();
#pragma unroll
    for (int o = 1; o < 1024; o <<= 1) {
        int v = (t >= o) ? sd[t - o] : 0;
        __syncthreads();
        sd[t] += v;
        __syncthreads();
    }
    part[t] = (t == 0) ? 0 : sd[t - 1];   // exclusive block prefix
}

__global__ __launch_bounds__(256) void scan3(const int* __restrict__ cnt, const int* __restrict__ part,
                                             int* __restrict__ offs, int* __restrict__ cur)
{
    __shared__ int sd[256];
    const int t = threadIdx.x;
    const int base = blockIdx.x*1024 + t*4;
    int v0 = 0, v1 = 0, v2 = 0, v3 = 0;
    if (base + 3 < NR) {
        int4 v = *reinterpret_cast<const int4*>(cnt + base);
        v0 = v.x; v1 = v.y; v2 = v.z; v3 = v.w;
    } else if (base < NR) {
        v0 = cnt[base];
        if (base + 1 < NR) v1 = cnt[base + 1];
        if (base + 2 < NR) v2 = cnt[base + 2];
    }
    sd[t] = v0 + v1 + v2 + v3;
    __syncthreads();
#pragma unroll
    for (int o = 1; o < 256; o <<= 1) {
        int vv = (t >= o) ? sd[t - o] : 0;
        __syncthreads();
        sd[t] += vv;
        __syncthreads();
    }
    const int excl = (t == 0) ? 0 : sd[t - 1];
    const int off = part[blockIdx.x] + excl;
    const int o0 = off, o1 = off + v0, o2 = off + v0 + v1, o3 = off + v0 + v1 + v2;
    if (base + 3 < NR) {
        int4 ov; ov.x = o0; ov.y = o1; ov.z = o2; ov.w = o3;
        *reinterpret_cast<int4*>(offs + base) = ov;
        *reinterpret_cast<int4*>(cur + base) = ov;
    } else if (base < NR) {
        offs[base] = o0; cur[base] = o0;
        if (base + 1 < NR) { offs[base+1] = o1; cur[base+1] = o1; }
        if (base + 2 < NR) { offs[base+2] = o2; cur[base+2] = o2; }
    }
}

__global__ __launch_bounds__(256) void fill_kernel(const int* __restrict__ rows,
                                                   const int* __restrict__ cols,
                                                   const float* __restrict__ vals,
                                                   int* __restrict__ cur,
                                                   int2* __restrict__ csr)
{
    int i = blockIdx.x*256 + threadIdx.x;
    const int stride = gridDim.x*256;
    for (; i < NEDGE; i += stride) {
        const int j = i >> 17;
        const int pos = atomicAdd(&cur[rows[i]*16 + j], 1);
        int2 ent; ent.x = cols[i]; ent.y = __float_as_int(vals[i]);
        csr[pos] = ent;
    }
}

// ---------------------------------------------------------------------------
// K2: one wave per row r, all 16 k-outputs in registers.
// Edge of A[j] row r contributes to k=j..j+2: acc[j+d] += M[j+d,j]*v*Yt[c][j+d][:].
// 64 lanes = 4 edge-slots x 16 feature-lanes; j-loop fully unrolled (static acc idx).
// ---------------------------------------------------------------------------
template<int J>
__device__ __forceinline__ void edge_batch(int p0, int esub, int fq, int nj, int bj,
    const int2* __restrict__ csr, const unsigned short* __restrict__ Yt,
    float w0, float w1, float w2, f32x4* acc)
{
    const int p = p0 + esub;
    const bool act = p < nj;
    const int pc = act ? p : nj - 1;
    const int2 ent = csr[bj + pc];
    const float v = act ? __int_as_float(ent.y) : 0.f;
    const int node = act ? ent.x : 0;          // keep masked-lane address in-bounds
    const unsigned short* yb = Yt + (size_t)node*1024 + J*64 + fq*4;
    {
        const uint2 uv = *reinterpret_cast<const uint2*>(yb);
        const float wv = w0 * v;
        acc[J][0] = fmaf(wv, lo16f(uv.x), acc[J][0]);
        acc[J][1] = fmaf(wv, hi16f(uv.x), acc[J][1]);
        acc[J][2] = fmaf(wv, lo16f(uv.y), acc[J][2]);
        acc[J][3] = fmaf(wv, hi16f(uv.y), acc[J][3]);
    }
    if constexpr (J < 15) {
        const uint2 uv = *reinterpret_cast<const uint2*>(yb + 64);
        const float wv = w1 * v;
        acc[J+1][0] = fmaf(wv, lo16f(uv.x), acc[J+1][0]);
        acc[J+1][1] = fmaf(wv, hi16f(uv.x), acc[J+1][1]);
        acc[J+1][2] = fmaf(wv, lo16f(uv.y), acc[J+1][2]);
        acc[J+1][3] = fmaf(wv, hi16f(uv.y), acc[J+1][3]);
    }
    if constexpr (J < 14) {
        const uint2 uv = *reinterpret_cast<const uint2*>(yb + 128);
        const float wv = w2 * v;
        acc[J+2][0] = fmaf(wv, lo16f(uv.x), acc[J+2][0]);
        acc[J+2][1] = fmaf(wv, hi16f(uv.x), acc[J+2][1]);
        acc[J+2][2] = fmaf(wv, lo16f(uv.y), acc[J+2][2]);
        acc[J+2][3] = fmaf(wv, hi16f(uv.y), acc[J+2][3]);
    }
}

__global__ __launch_bounds__(256) void k2_spmm(
    const unsigned short* __restrict__ Yt, const float* __restrict__ M,
    const int* __restrict__ offs, const int* __restrict__ cnt,
    const int2* __restrict__ csr, float* __restrict__ out)
{
    const int wid  = threadIdx.x >> 6;
    const int lane = threadIdx.x & 63;
    const int esub = lane >> 4;   // edge slot 0..3
    const int fq   = lane & 15;   // feature quad: f = fq*4 .. fq*4+3
    const int r = blockIdx.x*4 + wid;   // 12500*4 = 50000 exact

    // coalesced per-row setup: lane fq holds j=fq's base/count
    const int off_l = offs[r*16 + fq];
    const int cnt_l = cnt [r*16 + fq];

    f32x4 acc[16];
#pragma unroll
    for (int k = 0; k < 16; ++k) acc[k] = (f32x4){0.f, 0.f, 0.f, 0.f};

#define PER_J(J)                                                               \
    {                                                                          \
        const int bj = __builtin_amdgcn_readlane(off_l, J);                    \
        const int nj = __builtin_amdgcn_readlane(cnt_l, J);                    \
        const float w0 = M[J*17];                                              \
        const float w1 = (J < 15) ? M[J*17 + 16] : 0.f;                        \
        const float w2 = (J < 14) ? M[J*17 + 32] : 0.f;                        \
        if (nj > 0) {                                                          \
            edge_batch<J>(0, esub, fq, nj, bj, csr, Yt, w0, w1, w2, acc);      \
            for (int p0 = 4; p0 < nj; p0 += 4)                                 \
                edge_batch<J>(p0, esub, fq, nj, bj, csr, Yt, w0, w1, w2, acc); \
        }                                                                      \
    }
    PER_J(0)  PER_J(1)  PER_J(2)  PER_J(3)
    PER_J(4)  PER_J(5)  PER_J(6)  PER_J(7)
    PER_J(8)  PER_J(9)  PER_J(10) PER_J(11)
    PER_J(12) PER_J(13) PER_J(14) PER_J(15)
#undef PER_J

    // reduce across the 4 edge-slots, then store (one float4 per k)
#pragma unroll
    for (int k = 0; k < 16; ++k) {
#pragma unroll
        for (int u = 0; u < 4; ++u) {
            acc[k][u] += __shfl_xor(acc[k][u], 16);
            acc[k][u] += __shfl_xor(acc[k][u], 32);
        }
    }
    if (esub == 0) {
#pragma unroll
        for (int k = 0; k < 16; ++k) {
            float4 res; res.x = acc[k][0]; res.y = acc[k][1];
            res.z = acc[k][2]; res.w = acc[k][3];
            *reinterpret_cast<float4*>(out + ((size_t)k*NN + r)*FF + fq*4) = res;
        }
    }
}

// ---------------------------------------------------------------------------
extern "C" void kernel_launch(void* const* d_in, const int* in_sizes, int n_in,
                              void* d_out, int out_size, void* d_ws, size_t ws_size,
                              hipStream_t stream) {
    (void)in_sizes; (void)n_in; (void)out_size; (void)ws_size;
    const float* x     = (const float*)d_in[0];
    const float* M     = (const float*)d_in[1];
    const float* avals = (const float*)d_in[2];
    const float* W     = (const float*)d_in[3];
    const int*   arows = (const int*)d_in[4];
    const int*   acols = (const int*)d_in[5];
    float* out = (float*)d_out;

    // workspace carve (total ~128.8 MB)
    char* ws = (char*)d_ws;
    size_t o = 0;
    unsigned short* Yt = (unsigned short*)(ws + o); o += (size_t)TT*NN*FF*2;  // 102.4 MB
    o = (o + 255) & ~(size_t)255;
    int* cnt  = (int*)(ws + o); o += (size_t)NR*4; o = (o + 255) & ~(size_t)255;
    int* offs = (int*)(ws + o); o += (size_t)NR*4; o = (o + 255) & ~(size_t)255;
    int* cur  = (int*)(ws + o); o += (size_t)NR*4; o = (o + 255) & ~(size_t)255;
    int* part = (int*)(ws + o); o += 4096;          o = (o + 255) & ~(size_t)255;
    int2* csr = (int2*)(ws + o);                    // 16.8 MB

    hipMemsetAsync(cnt, 0, (size_t)NR*4, stream);
    hipLaunchKernelGGL(k1_proj_mix, dim3(2048), dim3(256), 0, stream, x, M, W, Yt);
    hipLaunchKernelGGL(count_kernel, dim3(2048), dim3(256), 0, stream, arows, cnt);
    hipLaunchKernelGGL(scan1, dim3(SCAN_NBLK), dim3(256), 0, stream, cnt, part);
    hipLaunchKernelGGL(scan2, dim3(1), dim3(1024), 0, stream, part);
    hipLaunchKernelGGL(scan3, dim3(SCAN_NBLK), dim3(256), 0, stream, cnt, part, offs, cur);
    hipLaunchKernelGGL(fill_kernel, dim3(2048), dim3(256), 0, stream, arows, acols, avals, cur, csr);
    hipLaunchKernelGGL(k2_spmm, dim3(12500), dim3(256), 0, stream, Yt, M, offs, cnt, csr, out);
}

// Round 5
// 491.473 us; speedup vs baseline: 1.3198x; 1.2566x over previous
//
#include <hip/hip_runtime.h>

// Problem constants
#define TT 16
#define NN 50000
#define FF 64
#define EE 131072
#define NR (TT*NN)            // 800000 (r,j) pairs
#define NEDGE (TT*EE)         // 2097152 edges total
#define SCAN_NBLK ((NR + 1023) / 1024)   // 782

typedef __attribute__((ext_vector_type(8))) short bf16x8;
typedef __attribute__((ext_vector_type(4))) short bf16x4;
typedef __attribute__((ext_vector_type(4))) float f32x4;

__device__ __forceinline__ unsigned short f2bf(float f) {
    union { float f; unsigned u; } v; v.f = f;
    return (unsigned short)((v.u + 0x7FFFu + ((v.u >> 16) & 1u)) >> 16);  // RNE
}
__device__ __forceinline__ float lo16f(unsigned u) { return __uint_as_float(u << 16); }
__device__ __forceinline__ float hi16f(unsigned u) { return __uint_as_float(u & 0xFFFF0000u); }

// K=16 bf16 MFMA. A: lane holds A[m=lane&15][k=(lane>>4)*4+j];
// B: B[k=(lane>>4)*4+j][n=lane&15]; C/D: row=(lane>>4)*4+reg, col=lane&15.
__device__ __forceinline__ f32x4 mfma16x16x16bf16(bf16x4 a, bf16x4 b, f32x4 c) {
#if __has_builtin(__builtin_amdgcn_mfma_f32_16x16x16bf16_1k)
    return __builtin_amdgcn_mfma_f32_16x16x16bf16_1k(a, b, c, 0, 0, 0);
#elif __has_builtin(__builtin_amdgcn_mfma_f32_16x16x16_bf16)
    return __builtin_amdgcn_mfma_f32_16x16x16_bf16(a, b, c, 0, 0, 0);
#else
    f32x4 d;
    asm volatile("v_mfma_f32_16x16x16_bf16 %0, %1, %2, %3\n\ts_nop 7\n\ts_nop 7"
                 : "=&v"(d) : "v"(a), "v"(b), "v"(c));
    return d;
#endif
}

// ---------------------------------------------------------------------------
// K1: Yt[node][k][fo] (node-major) = sum_s M[k,s] * sum_fi x[s][node][fi]*W[fi][fo]
// One wave per node, fully in-register; mix MFMA computes (M@P)^T -> packed 8B stores.
// ---------------------------------------------------------------------------
__global__ __launch_bounds__(256) void k1_proj_mix(
    const float* __restrict__ x, const float* __restrict__ M,
    const float* __restrict__ W, unsigned short* __restrict__ Yt)
{
    const int tid  = threadIdx.x;
    const int wid  = tid >> 6;
    const int lane = tid & 63;
    const int col  = lane & 15;   // MFMA m/n index
    const int grp  = lane >> 4;   // MFMA k-group

    // W as B-frags for 16x16x32: lane holds B[k=q*32+grp*8+j][n=t*16+col]
    bf16x8 bw[2][4];
#pragma unroll
    for (int q = 0; q < 2; ++q)
#pragma unroll
        for (int t = 0; t < 4; ++t)
#pragma unroll
            for (int j = 0; j < 8; ++j)
                bw[q][t][j] = (short)f2bf(W[(q*32 + grp*8 + j)*FF + t*16 + col]);

    // M fragment: element j = M[col][grp*4+j] (B-frag of mix MFMA = M^T)
    bf16x4 mf;
#pragma unroll
    for (int j = 0; j < 4; ++j) mf[j] = (short)f2bf(M[col*16 + grp*4 + j]);

    const f32x4 zero = {0.f, 0.f, 0.f, 0.f};
    const int nwaves = gridDim.x * 4;

    for (int node = blockIdx.x*4 + wid; node < NN; node += nwaves) {
        // ---- load x rows direct to A-frags: lane reads row s=col, fi = q*32+grp*8+(0..7) ----
        const float* xb = x + (size_t)col*NN*FF + (size_t)node*FF + grp*8;
        float4 v0 = *reinterpret_cast<const float4*>(xb);
        float4 v1 = *reinterpret_cast<const float4*>(xb + 4);
        float4 v2 = *reinterpret_cast<const float4*>(xb + 32);
        float4 v3 = *reinterpret_cast<const float4*>(xb + 36);
        bf16x8 a0, a1;
        a0[0] = (short)f2bf(v0.x); a0[1] = (short)f2bf(v0.y);
        a0[2] = (short)f2bf(v0.z); a0[3] = (short)f2bf(v0.w);
        a0[4] = (short)f2bf(v1.x); a0[5] = (short)f2bf(v1.y);
        a0[6] = (short)f2bf(v1.z); a0[7] = (short)f2bf(v1.w);
        a1[0] = (short)f2bf(v2.x); a1[1] = (short)f2bf(v2.y);
        a1[2] = (short)f2bf(v2.z); a1[3] = (short)f2bf(v2.w);
        a1[4] = (short)f2bf(v3.x); a1[5] = (short)f2bf(v3.y);
        a1[6] = (short)f2bf(v3.z); a1[7] = (short)f2bf(v3.w);

        // ---- P[s][fo] = X @ W via 16x16x32 MFMA (K=64 in 2 steps, 4 fo-tiles) ----
        f32x4 acc[4];
#pragma unroll
        for (int t = 0; t < 4; ++t) acc[t] = zero;
#pragma unroll
        for (int t = 0; t < 4; ++t)
            acc[t] = __builtin_amdgcn_mfma_f32_16x16x32_bf16(a0, bw[0][t], acc[t], 0, 0, 0);
#pragma unroll
        for (int t = 0; t < 4; ++t)
            acc[t] = __builtin_amdgcn_mfma_f32_16x16x32_bf16(a1, bw[1][t], acc[t], 0, 0, 0);

        // ---- Y^T = P^T @ M^T: lane holds Y[k=col][fo=t*16+grp*4+rr] -> packed 8B store,
        //      node-major layout: Yt[node*1024 + k*64 + fo]
#pragma unroll
        for (int t = 0; t < 4; ++t) {
            bf16x4 pb;
#pragma unroll
            for (int rr = 0; rr < 4; ++rr) pb[rr] = (short)f2bf(acc[t][rr]);
            f32x4 y = mfma16x16x16bf16(pb, mf, zero);
            unsigned lo = (unsigned)f2bf(y[0]) | ((unsigned)f2bf(y[1]) << 16);
            unsigned hi = (unsigned)f2bf(y[2]) | ((unsigned)f2bf(y[3]) << 16);
            uint2 st; st.x = lo; st.y = hi;
            *reinterpret_cast<uint2*>(Yt + (size_t)node*1024 + col*64 + t*16 + grp*4) = st;
        }
    }
}

// ---------------------------------------------------------------------------
// CSR build with row-major (r,j) indexing: cnt/offs/cur at [r*16 + j].
// csr entries of one row r (all 16 j lists) end up contiguous.
// ---------------------------------------------------------------------------
__global__ __launch_bounds__(256) void count_kernel(const int* __restrict__ rows,
                                                    int* __restrict__ cnt)
{
    int i = blockIdx.x*256 + threadIdx.x;
    const int stride = gridDim.x*256;
    for (; i < NEDGE; i += stride) {
        const int j = i >> 17;            // EE = 2^17
        atomicAdd(&cnt[rows[i]*16 + j], 1);
    }
}

__global__ __launch_bounds__(256) void scan1(const int* __restrict__ cnt, int* __restrict__ part)
{
    __shared__ int sd[256];
    const int t = threadIdx.x;
    const int base = blockIdx.x*1024 + t*4;
    int s = 0;
    if (base + 3 < NR) {
        int4 v = *reinterpret_cast<const int4*>(cnt + base);
        s = v.x + v.y + v.z + v.w;
    } else if (base < NR) {
        for (int u = 0; u < 4; ++u) if (base + u < NR) s += cnt[base + u];
    }
    sd[t] = s; __syncthreads();
#pragma unroll
    for (int o = 128; o > 0; o >>= 1) {
        if (t < o) sd[t] += sd[t + o];
        __syncthreads();
    }
    if (t == 0) part[blockIdx.x] = sd[0];
}

__global__ __launch_bounds__(1024) void scan2(int* __restrict__ part)
{
    __shared__ int sd[1024];
    const int t = threadIdx.x;
    sd[t] = (t < SCAN_NBLK) ? part[t] : 0;
    __syncthreads();
#pragma unroll
    for (int o = 1; o < 1024; o <<= 1) {
        int v = (t >= o) ? sd[t - o] : 0;
        __syncthreads();
        sd[t] += v;
        __syncthreads();
    }
    part[t] = (t == 0) ? 0 : sd[t - 1];   // exclusive block prefix
}

__global__ __launch_bounds__(256) void scan3(const int* __restrict__ cnt, const int* __restrict__ part,
                                             int* __restrict__ offs, int* __restrict__ cur)
{
    __shared__ int sd[256];
    const int t = threadIdx.x;
    const int base = blockIdx.x*1024 + t*4;
    int v0 = 0, v1 = 0, v2 = 0, v3 = 0;
    if (base + 3 < NR) {
        int4 v = *reinterpret_cast<const int4*>(cnt + base);
        v0 = v.x; v1 = v.y; v2 = v.z; v3 = v.w;
    } else if (base < NR) {
        v0 = cnt[base];
        if (base + 1 < NR) v1 = cnt[base + 1];
        if (base + 2 < NR) v2 = cnt[base + 2];
    }
    sd[t] = v0 + v1 + v2 + v3;
    __syncthreads();
#pragma unroll
    for (int o = 1; o < 256; o <<= 1) {
        int vv = (t >= o) ? sd[t - o] : 0;
        __syncthreads();
        sd[t] += vv;
        __syncthreads();
    }
    const int excl = (t == 0) ? 0 : sd[t - 1];
    const int off = part[blockIdx.x] + excl;
    const int o0 = off, o1 = off + v0, o2 = off + v0 + v1, o3 = off + v0 + v1 + v2;
    if (base + 3 < NR) {
        int4 ov; ov.x = o0; ov.y = o1; ov.z = o2; ov.w = o3;
        *reinterpret_cast<int4*>(offs + base) = ov;
        *reinterpret_cast<int4*>(cur + base) = ov;
    } else if (base < NR) {
        offs[base] = o0; cur[base] = o0;
        if (base + 1 < NR) { offs[base+1] = o1; cur[base+1] = o1; }
        if (base + 2 < NR) { offs[base+2] = o2; cur[base+2] = o2; }
    }
}

__global__ __launch_bounds__(256) void fill_kernel(const int* __restrict__ rows,
                                                   const int* __restrict__ cols,
                                                   const float* __restrict__ vals,
                                                   int* __restrict__ cur,
                                                   int2* __restrict__ csr)
{
    int i = blockIdx.x*256 + threadIdx.x;
    const int stride = gridDim.x*256;
    for (; i < NEDGE; i += stride) {
        const int j = i >> 17;
        const int pos = atomicAdd(&cur[rows[i]*16 + j], 1);
        int2 ent; ent.x = cols[i]; ent.y = __float_as_int(vals[i]);
        csr[pos] = ent;
    }
}

// ---------------------------------------------------------------------------
// K2: one wave per row r, all 16 k-outputs in registers.
// The row's entire edge list (contiguous across j, avg 42, max ~70) is
// preloaded into a per-wave LDS buffer with 2 coalesced loads. Sections then
// have a 1-deep global chain (Yt gather only). Pass 1 = straight-line masked
// first batch of all 16 sections (deep gather pipelining); pass 2 = residuals.
// ---------------------------------------------------------------------------
template<int J>
__device__ __forceinline__ void k2_batch(int p0, int nj, int sbase, int esub, int fq,
    const int2* eb, const unsigned short* __restrict__ Yt,
    const float* __restrict__ M, f32x4* acc)
{
    const int p = p0 + esub;
    const bool act = p < nj;
    const int li = act ? (sbase + p) : 0;
    const int2 ent = eb[li];                  // LDS read (broadcast across 16 flanes)
    const float v = act ? __int_as_float(ent.y) : 0.f;
    const int node = act ? ent.x : 0;         // keep masked-lane address in-bounds
    const unsigned short* yb = Yt + (size_t)node*1024 + J*64 + fq*4;
    const float w0 = M[J*17];                 // uniform scalar loads, CSE'd
    {
        const uint2 uv = *reinterpret_cast<const uint2*>(yb);
        const float wv = w0 * v;
        acc[J][0] = fmaf(wv, lo16f(uv.x), acc[J][0]);
        acc[J][1] = fmaf(wv, hi16f(uv.x), acc[J][1]);
        acc[J][2] = fmaf(wv, lo16f(uv.y), acc[J][2]);
        acc[J][3] = fmaf(wv, hi16f(uv.y), acc[J][3]);
    }
    if constexpr (J < 15) {
        const uint2 uv = *reinterpret_cast<const uint2*>(yb + 64);
        const float wv = M[J*17 + 16] * v;
        acc[J+1][0] = fmaf(wv, lo16f(uv.x), acc[J+1][0]);
        acc[J+1][1] = fmaf(wv, hi16f(uv.x), acc[J+1][1]);
        acc[J+1][2] = fmaf(wv, lo16f(uv.y), acc[J+1][2]);
        acc[J+1][3] = fmaf(wv, hi16f(uv.y), acc[J+1][3]);
    }
    if constexpr (J < 14) {
        const uint2 uv = *reinterpret_cast<const uint2*>(yb + 128);
        const float wv = M[J*17 + 32] * v;
        acc[J+2][0] = fmaf(wv, lo16f(uv.x), acc[J+2][0]);
        acc[J+2][1] = fmaf(wv, hi16f(uv.x), acc[J+2][1]);
        acc[J+2][2] = fmaf(wv, lo16f(uv.y), acc[J+2][2]);
        acc[J+2][3] = fmaf(wv, hi16f(uv.y), acc[J+2][3]);
    }
}

__global__ __launch_bounds__(256) void k2_spmm(
    const unsigned short* __restrict__ Yt, const float* __restrict__ M,
    const int* __restrict__ offs, const int* __restrict__ cnt,
    const int2* __restrict__ csr, float* __restrict__ out)
{
    __shared__ int2 ebuf[4][128];
    const int wid  = threadIdx.x >> 6;
    const int lane = threadIdx.x & 63;
    const int esub = lane >> 4;   // edge slot 0..3
    const int fq   = lane & 15;   // feature quad: f = fq*4 .. fq*4+3
    const int r = blockIdx.x*4 + wid;   // 12500*4 = 50000 exact

    // coalesced setup: lane fq holds j=fq's count; readlane -> SGPR prefix
    const int cl = cnt[r*16 + fq];
    int c[16], cum[16];
#pragma unroll
    for (int j = 0; j < 16; ++j) c[j] = __builtin_amdgcn_readlane(cl, j);
    cum[0] = 0;
#pragma unroll
    for (int j = 1; j < 16; ++j) cum[j] = cum[j-1] + c[j-1];
    const int ntot = cum[15] + c[15];
    const int base = __builtin_amdgcn_readfirstlane(offs[r*16]);

    // preload the whole row's edge list into LDS (2 coalesced 512B loads)
    int2* eb = ebuf[wid];
    if (lane < ntot)      eb[lane]      = csr[base + lane];
    if (lane + 64 < ntot) eb[lane + 64] = csr[base + lane + 64];

    f32x4 acc[16];
#pragma unroll
    for (int k = 0; k < 16; ++k) acc[k] = (f32x4){0.f, 0.f, 0.f, 0.f};

    // pass 1: first batch of every section, straight-line (masked, no branches)
#define P1(J) k2_batch<J>(0, c[J], cum[J], esub, fq, eb, Yt, M, acc);
    P1(0)  P1(1)  P1(2)  P1(3)  P1(4)  P1(5)  P1(6)  P1(7)
    P1(8)  P1(9)  P1(10) P1(11) P1(12) P1(13) P1(14) P1(15)
#undef P1

    // pass 2: residual batches (uniform trip counts, usually zero)
#define P2(J) for (int p0 = 4; p0 < c[J]; p0 += 4) \
        k2_batch<J>(p0, c[J], cum[J], esub, fq, eb, Yt, M, acc);
    P2(0)  P2(1)  P2(2)  P2(3)  P2(4)  P2(5)  P2(6)  P2(7)
    P2(8)  P2(9)  P2(10) P2(11) P2(12) P2(13) P2(14) P2(15)
#undef P2

    // reduce across the 4 edge-slots, then store (one float4 per k)
#pragma unroll
    for (int k = 0; k < 16; ++k) {
#pragma unroll
        for (int u = 0; u < 4; ++u) {
            acc[k][u] += __shfl_xor(acc[k][u], 16);
            acc[k][u] += __shfl_xor(acc[k][u], 32);
        }
    }
    if (esub == 0) {
#pragma unroll
        for (int k = 0; k < 16; ++k) {
            float4 res; res.x = acc[k][0]; res.y = acc[k][1];
            res.z = acc[k][2]; res.w = acc[k][3];
            *reinterpret_cast<float4*>(out + ((size_t)k*NN + r)*FF + fq*4) = res;
        }
    }
}

// ---------------------------------------------------------------------------
extern "C" void kernel_launch(void* const* d_in, const int* in_sizes, int n_in,
                              void* d_out, int out_size, void* d_ws, size_t ws_size,
                              hipStream_t stream) {
    (void)in_sizes; (void)n_in; (void)out_size; (void)ws_size;
    const float* x     = (const float*)d_in[0];
    const float* M     = (const float*)d_in[1];
    const float* avals = (const float*)d_in[2];
    const float* W     = (const float*)d_in[3];
    const int*   arows = (const int*)d_in[4];
    const int*   acols = (const int*)d_in[5];
    float* out = (float*)d_out;

    // workspace carve (total ~128.8 MB)
    char* ws = (char*)d_ws;
    size_t o = 0;
    unsigned short* Yt = (unsigned short*)(ws + o); o += (size_t)TT*NN*FF*2;  // 102.4 MB
    o = (o + 255) & ~(size_t)255;
    int* cnt  = (int*)(ws + o); o += (size_t)NR*4; o = (o + 255) & ~(size_t)255;
    int* offs = (int*)(ws + o); o += (size_t)NR*4; o = (o + 255) & ~(size_t)255;
    int* cur  = (int*)(ws + o); o += (size_t)NR*4; o = (o + 255) & ~(size_t)255;
    int* part = (int*)(ws + o); o += 4096;          o = (o + 255) & ~(size_t)255;
    int2* csr = (int2*)(ws + o);                    // 16.8 MB

    hipMemsetAsync(cnt, 0, (size_t)NR*4, stream);
    hipLaunchKernelGGL(k1_proj_mix, dim3(2048), dim3(256), 0, stream, x, M, W, Yt);
    hipLaunchKernelGGL(count_kernel, dim3(2048), dim3(256), 0, stream, arows, cnt);
    hipLaunchKernelGGL(scan1, dim3(SCAN_NBLK), dim3(256), 0, stream, cnt, part);
    hipLaunchKernelGGL(scan2, dim3(1), dim3(1024), 0, stream, part);
    hipLaunchKernelGGL(scan3, dim3(SCAN_NBLK), dim3(256), 0, stream, cnt, part, offs, cur);
    hipLaunchKernelGGL(fill_kernel, dim3(2048), dim3(256), 0, stream, arows, acols, avals, cur, csr);
    hipLaunchKernelGGL(k2_spmm, dim3(12500), dim3(256), 0, stream, Yt, M, offs, cnt, csr, out);
}

// Round 6
// 365.244 us; speedup vs baseline: 1.7759x; 1.3456x over previous
//
#include <hip/hip_runtime.h>

// Problem constants
#define TT 16
#define NN 50000
#define FF 64
#define EE 131072
#define NEDGE (TT*EE)          // 2097152 = 8192*256 exactly
#define RPB 32                 // rows per k2 block
#define NRANGE ((NN + RPB - 1) / RPB)   // 1563
#define NSUB 8                 // XCD-proxy sub-buckets per range
#define BCAP 256               // capacity per sub-bucket (mean 160, +7.6 sigma)
#define NBUCK (NRANGE*NSUB)    // 12504

typedef __attribute__((ext_vector_type(8))) short bf16x8;
typedef __attribute__((ext_vector_type(4))) short bf16x4;
typedef __attribute__((ext_vector_type(4))) float f32x4;

__device__ __forceinline__ unsigned short f2bf(float f) {
    union { float f; unsigned u; } v; v.f = f;
    return (unsigned short)((v.u + 0x7FFFu + ((v.u >> 16) & 1u)) >> 16);  // RNE
}
__device__ __forceinline__ float lo16f(unsigned u) { return __uint_as_float(u << 16); }
__device__ __forceinline__ float hi16f(unsigned u) { return __uint_as_float(u & 0xFFFF0000u); }

// K=16 bf16 MFMA. A: lane holds A[m=lane&15][k=(lane>>4)*4+j];
// B: B[k=(lane>>4)*4+j][n=lane&15]; C/D: row=(lane>>4)*4+reg, col=lane&15.
__device__ __forceinline__ f32x4 mfma16x16x16bf16(bf16x4 a, bf16x4 b, f32x4 c) {
#if __has_builtin(__builtin_amdgcn_mfma_f32_16x16x16bf16_1k)
    return __builtin_amdgcn_mfma_f32_16x16x16bf16_1k(a, b, c, 0, 0, 0);
#elif __has_builtin(__builtin_amdgcn_mfma_f32_16x16x16_bf16)
    return __builtin_amdgcn_mfma_f32_16x16x16_bf16(a, b, c, 0, 0, 0);
#else
    f32x4 d;
    asm volatile("v_mfma_f32_16x16x16_bf16 %0, %1, %2, %3\n\ts_nop 7\n\ts_nop 7"
                 : "=&v"(d) : "v"(a), "v"(b), "v"(c));
    return d;
#endif
}

// ---------------------------------------------------------------------------
// K1: Yt[node][k][fo] (node-major) = sum_s M[k,s] * sum_fi x[s][node][fi]*W[fi][fo]
// One wave per node, fully in-register; mix MFMA computes (M@P)^T -> packed 8B stores.
// ---------------------------------------------------------------------------
__global__ __launch_bounds__(256) void k1_proj_mix(
    const float* __restrict__ x, const float* __restrict__ M,
    const float* __restrict__ W, unsigned short* __restrict__ Yt)
{
    const int tid  = threadIdx.x;
    const int wid  = tid >> 6;
    const int lane = tid & 63;
    const int col  = lane & 15;   // MFMA m/n index
    const int grp  = lane >> 4;   // MFMA k-group

    // W as B-frags for 16x16x32: lane holds B[k=q*32+grp*8+j][n=t*16+col]
    bf16x8 bw[2][4];
#pragma unroll
    for (int q = 0; q < 2; ++q)
#pragma unroll
        for (int t = 0; t < 4; ++t)
#pragma unroll
            for (int j = 0; j < 8; ++j)
                bw[q][t][j] = (short)f2bf(W[(q*32 + grp*8 + j)*FF + t*16 + col]);

    // M fragment: element j = M[col][grp*4+j] (B-frag of mix MFMA = M^T)
    bf16x4 mf;
#pragma unroll
    for (int j = 0; j < 4; ++j) mf[j] = (short)f2bf(M[col*16 + grp*4 + j]);

    const f32x4 zero = {0.f, 0.f, 0.f, 0.f};
    const int nwaves = gridDim.x * 4;

    for (int node = blockIdx.x*4 + wid; node < NN; node += nwaves) {
        // ---- load x rows direct to A-frags: lane reads row s=col, fi = q*32+grp*8+(0..7) ----
        const float* xb = x + (size_t)col*NN*FF + (size_t)node*FF + grp*8;
        float4 v0 = *reinterpret_cast<const float4*>(xb);
        float4 v1 = *reinterpret_cast<const float4*>(xb + 4);
        float4 v2 = *reinterpret_cast<const float4*>(xb + 32);
        float4 v3 = *reinterpret_cast<const float4*>(xb + 36);
        bf16x8 a0, a1;
        a0[0] = (short)f2bf(v0.x); a0[1] = (short)f2bf(v0.y);
        a0[2] = (short)f2bf(v0.z); a0[3] = (short)f2bf(v0.w);
        a0[4] = (short)f2bf(v1.x); a0[5] = (short)f2bf(v1.y);
        a0[6] = (short)f2bf(v1.z); a0[7] = (short)f2bf(v1.w);
        a1[0] = (short)f2bf(v2.x); a1[1] = (short)f2bf(v2.y);
        a1[2] = (short)f2bf(v2.z); a1[3] = (short)f2bf(v2.w);
        a1[4] = (short)f2bf(v3.x); a1[5] = (short)f2bf(v3.y);
        a1[6] = (short)f2bf(v3.z); a1[7] = (short)f2bf(v3.w);

        // ---- P[s][fo] = X @ W via 16x16x32 MFMA (K=64 in 2 steps, 4 fo-tiles) ----
        f32x4 acc[4];
#pragma unroll
        for (int t = 0; t < 4; ++t) acc[t] = zero;
#pragma unroll
        for (int t = 0; t < 4; ++t)
            acc[t] = __builtin_amdgcn_mfma_f32_16x16x32_bf16(a0, bw[0][t], acc[t], 0, 0, 0);
#pragma unroll
        for (int t = 0; t < 4; ++t)
            acc[t] = __builtin_amdgcn_mfma_f32_16x16x32_bf16(a1, bw[1][t], acc[t], 0, 0, 0);

        // ---- Y^T = P^T @ M^T: lane holds Y[k=col][fo=t*16+grp*4+rr] -> packed 8B store
#pragma unroll
        for (int t = 0; t < 4; ++t) {
            bf16x4 pb;
#pragma unroll
            for (int rr = 0; rr < 4; ++rr) pb[rr] = (short)f2bf(acc[t][rr]);
            f32x4 y = mfma16x16x16bf16(pb, mf, zero);
            unsigned lo = (unsigned)f2bf(y[0]) | ((unsigned)f2bf(y[1]) << 16);
            unsigned hi = (unsigned)f2bf(y[2]) | ((unsigned)f2bf(y[3]) << 16);
            uint2 st; st.x = lo; st.y = hi;
            *reinterpret_cast<uint2*>(Yt + (size_t)node*1024 + col*64 + t*16 + grp*4) = st;
        }
    }
}

// ---------------------------------------------------------------------------
// append: one thread per edge. Bucket = (row/32)*8 + (blockIdx&7) so each
// sub-bucket is appended (dense, sequential positions) by ~one XCD -> full
// 64B lines, no write amplification. Entry: {col | key<<16, val},
// key = (r&31)*16 + j (9 bits).
// ---------------------------------------------------------------------------
__global__ __launch_bounds__(256) void append_kernel(
    const int* __restrict__ rows, const int* __restrict__ cols,
    const float* __restrict__ vals, int* __restrict__ bcnt,
    int2* __restrict__ btmp)
{
    const int i = blockIdx.x*256 + threadIdx.x;   // grid sized exactly NEDGE
    const int r = rows[i];
    const int j = i >> 17;                        // EE = 2^17
    const int b = (r >> 5)*NSUB + (blockIdx.x & 7);
    const int pos = atomicAdd(&bcnt[b], 1);
    if (pos < BCAP) {
        int2 e;
        e.x = cols[i] | (((r & 31)*16 + j) << 16);
        e.y = __float_as_int(vals[i]);
        btmp[(size_t)b*BCAP + pos] = e;
    }
}

// ---------------------------------------------------------------------------
// k2_fused: block per 32-row range. Counting-sort the range's edges in LDS
// (count -> 512-scan -> scatter), then wave-per-8-rows gather/accumulate.
// ---------------------------------------------------------------------------
template<int J>
__device__ __forceinline__ void k2_batch(int p0, int nj, int sbase, int esub, int fq,
    const int2* eb, const unsigned short* __restrict__ Yt,
    const float* __restrict__ M, f32x4* acc)
{
    const int p = p0 + esub;
    const bool act = p < nj;
    const int li = act ? (sbase + p) : 0;
    const int2 ent = eb[li];                  // LDS read (broadcast across 16 flanes)
    const float v = act ? __int_as_float(ent.y) : 0.f;
    const int node = act ? ent.x : 0;         // masked lanes read Yt[0] (in-bounds)
    const unsigned short* yb = Yt + (size_t)node*1024 + J*64 + fq*4;
    {
        const uint2 uv = *reinterpret_cast<const uint2*>(yb);
        const float wv = M[J*17] * v;
        acc[J][0] = fmaf(wv, lo16f(uv.x), acc[J][0]);
        acc[J][1] = fmaf(wv, hi16f(uv.x), acc[J][1]);
        acc[J][2] = fmaf(wv, lo16f(uv.y), acc[J][2]);
        acc[J][3] = fmaf(wv, hi16f(uv.y), acc[J][3]);
    }
    if constexpr (J < 15) {
        const uint2 uv = *reinterpret_cast<const uint2*>(yb + 64);
        const float wv = M[J*17 + 16] * v;
        acc[J+1][0] = fmaf(wv, lo16f(uv.x), acc[J+1][0]);
        acc[J+1][1] = fmaf(wv, hi16f(uv.x), acc[J+1][1]);
        acc[J+1][2] = fmaf(wv, lo16f(uv.y), acc[J+1][2]);
        acc[J+1][3] = fmaf(wv, hi16f(uv.y), acc[J+1][3]);
    }
    if constexpr (J < 14) {
        const uint2 uv = *reinterpret_cast<const uint2*>(yb + 128);
        const float wv = M[J*17 + 32] * v;
        acc[J+2][0] = fmaf(wv, lo16f(uv.x), acc[J+2][0]);
        acc[J+2][1] = fmaf(wv, hi16f(uv.x), acc[J+2][1]);
        acc[J+2][2] = fmaf(wv, lo16f(uv.y), acc[J+2][2]);
        acc[J+2][3] = fmaf(wv, hi16f(uv.y), acc[J+2][3]);
    }
}

__global__ __launch_bounds__(256) void k2_fused(
    const unsigned short* __restrict__ Yt, const float* __restrict__ M,
    const int* __restrict__ bcnt, const int2* __restrict__ btmp,
    float* __restrict__ out)
{
    __shared__ int2 sbuf[NSUB*BCAP];   // 16KB sorted edges
    __shared__ int scnt[RPB*16];       // counts per (r_local, j)
    __shared__ int soff[RPB*16];       // exclusive offsets
    __shared__ int scur[RPB*16];       // scatter cursors
    __shared__ int pscan[256];

    const int tid = threadIdx.x;
    const int blk = blockIdx.x;

    scnt[tid] = 0; scnt[tid + 256] = 0;
    __syncthreads();

    int bc[NSUB];
#pragma unroll
    for (int s = 0; s < NSUB; ++s) {
        int c = bcnt[blk*NSUB + s];
        bc[s] = c < BCAP ? c : BCAP;
    }
    const int2* bt = btmp + (size_t)blk*NSUB*BCAP;

    // count pass
#pragma unroll
    for (int s = 0; s < NSUB; ++s)
        for (int e = tid; e < bc[s]; e += 256)
            atomicAdd(&scnt[((unsigned)bt[s*BCAP + e].x) >> 16], 1);
    __syncthreads();

    // exclusive scan over 512 counters (pair-sum + Hillis-Steele over 256)
    const int a0 = scnt[2*tid], a1 = scnt[2*tid + 1];
    const int ps = a0 + a1;
    pscan[tid] = ps;
    __syncthreads();
    for (int o = 1; o < 256; o <<= 1) {
        int v = (tid >= o) ? pscan[tid - o] : 0;
        __syncthreads();
        pscan[tid] += v;
        __syncthreads();
    }
    const int excl = pscan[tid] - ps;
    soff[2*tid] = excl;      soff[2*tid + 1] = excl + a0;
    scur[2*tid] = excl;      scur[2*tid + 1] = excl + a0;
    __syncthreads();

    // scatter pass (btmp re-read is L2-hot)
#pragma unroll
    for (int s = 0; s < NSUB; ++s)
        for (int e = tid; e < bc[s]; e += 256) {
            const int2 ent = bt[s*BCAP + e];
            const int key = ((unsigned)ent.x) >> 16;
            const int pos = atomicAdd(&scur[key], 1);
            int2 se; se.x = ent.x & 0xFFFF; se.y = ent.y;
            sbuf[pos] = se;
        }
    __syncthreads();

    // per-wave row processing: wave handles 8 rows sequentially
    const int wid  = tid >> 6;
    const int lane = tid & 63;
    const int esub = lane >> 4;
    const int fq   = lane & 15;

    for (int rr = 0; rr < RPB/4; ++rr) {
        const int rl = wid*(RPB/4) + rr;
        const int r  = blk*RPB + rl;
        const int cl = scnt[rl*16 + fq];
        const int ol = soff[rl*16 + fq];
        int c[16], sb[16];
#pragma unroll
        for (int j = 0; j < 16; ++j) {
            c[j]  = __builtin_amdgcn_readlane(cl, j);
            sb[j] = __builtin_amdgcn_readlane(ol, j);
        }

        f32x4 acc[16];
#pragma unroll
        for (int k = 0; k < 16; ++k) acc[k] = (f32x4){0.f, 0.f, 0.f, 0.f};

        // pass 1: first batch of every section, straight-line (deep gather pipeline)
#define P1(J) k2_batch<J>(0, c[J], sb[J], esub, fq, sbuf, Yt, M, acc);
        P1(0)  P1(1)  P1(2)  P1(3)  P1(4)  P1(5)  P1(6)  P1(7)
        P1(8)  P1(9)  P1(10) P1(11) P1(12) P1(13) P1(14) P1(15)
#undef P1
        // pass 2: residual batches (usually empty)
#define P2(J) for (int p0 = 4; p0 < c[J]; p0 += 4) \
            k2_batch<J>(p0, c[J], sb[J], esub, fq, sbuf, Yt, M, acc);
        P2(0)  P2(1)  P2(2)  P2(3)  P2(4)  P2(5)  P2(6)  P2(7)
        P2(8)  P2(9)  P2(10) P2(11) P2(12) P2(13) P2(14) P2(15)
#undef P2

#pragma unroll
        for (int k = 0; k < 16; ++k) {
#pragma unroll
            for (int u = 0; u < 4; ++u) {
                acc[k][u] += __shfl_xor(acc[k][u], 16);
                acc[k][u] += __shfl_xor(acc[k][u], 32);
            }
        }
        if (esub == 0 && r < NN) {
#pragma unroll
            for (int k = 0; k < 16; ++k) {
                float4 res; res.x = acc[k][0]; res.y = acc[k][1];
                res.z = acc[k][2]; res.w = acc[k][3];
                *reinterpret_cast<float4*>(out + ((size_t)k*NN + r)*FF + fq*4) = res;
            }
        }
    }
}

// ---------------------------------------------------------------------------
extern "C" void kernel_launch(void* const* d_in, const int* in_sizes, int n_in,
                              void* d_out, int out_size, void* d_ws, size_t ws_size,
                              hipStream_t stream) {
    (void)in_sizes; (void)n_in; (void)out_size; (void)ws_size;
    const float* x     = (const float*)d_in[0];
    const float* M     = (const float*)d_in[1];
    const float* avals = (const float*)d_in[2];
    const float* W     = (const float*)d_in[3];
    const int*   arows = (const int*)d_in[4];
    const int*   acols = (const int*)d_in[5];
    float* out = (float*)d_out;

    // workspace carve (~128.1 MB total)
    char* ws = (char*)d_ws;
    size_t o = 0;
    unsigned short* Yt = (unsigned short*)(ws + o); o += (size_t)TT*NN*FF*2;  // 102.4 MB
    o = (o + 255) & ~(size_t)255;
    int* bcnt = (int*)(ws + o); o += (size_t)NBUCK*4;  o = (o + 255) & ~(size_t)255;
    int2* btmp = (int2*)(ws + o);                      // 12504*256*8 = 25.6 MB

    hipMemsetAsync(bcnt, 0, (size_t)NBUCK*4, stream);
    hipLaunchKernelGGL(k1_proj_mix, dim3(2048), dim3(256), 0, stream, x, M, W, Yt);
    hipLaunchKernelGGL(append_kernel, dim3(NEDGE/256), dim3(256), 0, stream,
                       arows, acols, avals, bcnt, btmp);
    hipLaunchKernelGGL(k2_fused, dim3(NRANGE), dim3(256), 0, stream,
                       Yt, M, bcnt, btmp, out);
}